// Round 1
// baseline (2851.540 us; speedup 1.0000x reference)
//
#include <hip/hip_runtime.h>
#include <math.h>

#define EPSBN 1e-5f

// ---------------- workspace layout (float offsets) ----------------
static constexpr size_t EX_T  = 0;          // (16,20,20,256)  1638400
static constexpr size_t IN_T  = 1638400;    // (16,32,32,256)  4194304
static constexpr size_t WT2   = 5832704;    // (4,9,256,256)   2359296
static constexpr size_t FWT   = 8192000;    // (2,256,256)     131072
static constexpr size_t OM0   = 8323072;    // (16,27,18,18)   139968
static constexpr size_t OM1   = 8463040;    // (16,27,30,30)   388800
static constexpr size_t OM2   = 8851840;    // 139968
static constexpr size_t OM3   = 8991808;    // 388800
static constexpr size_t HOUT0 = 9380608;    // (16,256,324)    1327104
static constexpr size_t HOUT1 = 10707712;   // (16,256,900)    3686400
static constexpr size_t HOUT2 = 14394112;   // 1327104
static constexpr size_t HOUT3 = 15721216;   // 3686400
static constexpr size_t XCB   = 19407616;   // (2,16,256,169)  2768896
// total 22176512 floats = 88.7 MB

// ---------------- NCHW -> NHWC transpose (C=256) ----------------
__global__ __launch_bounds__(256) void k_transpose(const float* __restrict__ in,
                                                   float* __restrict__ out,
                                                   int H, int W) {
  int y = blockIdx.x, b = blockIdx.y;
  __shared__ float tile[32][257];
  int t = threadIdx.x;
  int x = t & 31, cb = t >> 5;
  for (int c0 = 0; c0 < 256; c0 += 8) {
    int c = c0 + cb;
    if (x < W) tile[x][c] = in[(((size_t)b * 256 + c) * H + y) * W + x];
  }
  __syncthreads();
  for (int x2 = 0; x2 < W; ++x2)
    out[((((size_t)b * H + y) * W + x2) << 8) + t] = tile[x2][t];
}

// ---------------- dcn_w (4,256,256,3,3) -> (4,9,256,256) [h][k][c][o] ----------------
__global__ __launch_bounds__(256) void k_wt(const float* __restrict__ w,
                                            float* __restrict__ wt) {
  int idx = blockIdx.x * 256 + threadIdx.x;           // < 2359296
  if (idx >= 4 * 9 * 256 * 256) return;
  int o = idx & 255;
  int c = (idx >> 8) & 255;
  int hk = idx >> 16;                                  // h*9 + k
  int k = hk % 9, h = hk / 9;
  wt[idx] = w[((size_t)((h * 256 + o) * 256 + c)) * 9 + k];
}

// ---------------- fus_w (2,256,256)[i][o][c] -> fwt [i][c][o] ----------------
__global__ __launch_bounds__(256) void k_fwt(const float* __restrict__ w,
                                             float* __restrict__ wt) {
  int idx = blockIdx.x * 256 + threadIdx.x;            // < 131072
  int o = idx & 255, c = (idx >> 8) & 255, i = idx >> 16;
  wt[idx] = w[(i << 16) + (o << 8) + c];
}

// ---------------- offset conv: om[h] = conv3x3(x, off_w[h]) + off_b[h] ----------------
__global__ __launch_bounds__(256) void k_offconv(const float* __restrict__ ex,
                                                 const float* __restrict__ inst,
                                                 const float* __restrict__ off_w,
                                                 const float* __restrict__ off_b,
                                                 float* __restrict__ ws) {
  int h = blockIdx.z & 3, b = blockIdx.z >> 2;
  int i = blockIdx.x;
  int o = blockIdx.y * 8 + threadIdx.y;
  int j = threadIdx.x;
  int H = (h & 1) ? 32 : 20;
  int W = H, ho = H - 2, wo = W - 2;
  if (i >= ho || o >= 27 || j >= wo) return;
  const size_t OMO[4] = {OM0, OM1, OM2, OM3};
  const float* x = (h & 1) ? inst : ex;
  float acc = off_b[h * 27 + o];
  const float* wbase = off_w + (size_t)(h * 27 + o) * 2304;   // [c][9]
  const float* xbase = x + ((size_t)b * 256 * H + i) * W + j;
  for (int c = 0; c < 256; ++c) {
    const float* xr = xbase + (size_t)c * H * W;
    const float* wr = wbase + c * 9;
    #pragma unroll
    for (int ky = 0; ky < 3; ++ky)
      #pragma unroll
      for (int kx = 0; kx < 3; ++kx)
        acc = fmaf(xr[ky * W + kx], wr[ky * 3 + kx], acc);
  }
  ws[OMO[h] + ((size_t)(b * 27 + o) * ho + i) * wo + j] = acc;
}

// ---------------- main deformable GEMM, bn1 folded ----------------
// block: 256 thr; tile: 256 o x 64 pixels; K = 9k * 256c chunked as 18 x (k, 128c)
__global__ __launch_bounds__(256) void k_dgemm(float* __restrict__ ws,
                                               const float* __restrict__ dcn_b,
                                               const float* __restrict__ g1,
                                               const float* __restrict__ b1,
                                               const float* __restrict__ m1,
                                               const float* __restrict__ v1) {
  const int h = blockIdx.z;
  const int HH4[4] = {20, 32, 20, 32};
  const size_t OMO[4] = {OM0, OM1, OM2, OM3};
  const size_t HOO[4] = {HOUT0, HOUT1, HOUT2, HOUT3};
  const int H = HH4[h], W = H, ho = H - 2, wo = W - 2, P = ho * wo;
  const int nblk = (P + 63) >> 6;
  if (blockIdx.x >= nblk) return;          // uniform per block
  const int b = blockIdx.y;
  const int p0 = blockIdx.x << 6;
  const float* xt = ws + ((h & 1) ? IN_T : EX_T);
  const float* om = ws + OMO[h] + (size_t)b * 27 * P;
  const float* wt = ws + WT2 + (size_t)h * 9 * 65536;
  float* outp = ws + HOO[h] + (size_t)b * 256 * P;

  __shared__ float swt[576][4];
  __shared__ int   sad[576][4];
  __shared__ float S[64][129];

  const int t = threadIdx.x;

  // Phase A: per-(pixel,k) bilinear tables (weights incl. mask & validity, base addrs)
  for (int e = t; e < 576; e += 256) {
    int pl = e / 9, k = e - pl * 9;
    float w4[4] = {0.f, 0.f, 0.f, 0.f};
    int a4[4] = {0, 0, 0, 0};
    int p = p0 + pl;
    if (p < P) {
      int i = p / wo, j = p - i * wo;
      float oy = om[(2 * k) * P + p];
      float ox = om[(2 * k + 1) * P + p];
      float mm = om[(18 + k) * P + p];
      float msk = 1.f / (1.f + __expf(-mm));
      int ky = k / 3, kx = k - ky * 3;
      float py = (float)(ky + i) + oy;
      float px = (float)(kx + j) + ox;
      float fy = floorf(py), fx = floorf(px);
      int y0 = (int)fy, x0 = (int)fx;
      float dy = py - fy, dx = px - fx;
      #pragma unroll
      for (int q = 0; q < 4; ++q) {
        int yy = y0 + (q >> 1), xx = x0 + (q & 1);
        bool vld = (yy >= 0) && (yy < H) && (xx >= 0) && (xx < W);
        int yc = min(max(yy, 0), H - 1), xc = min(max(xx, 0), W - 1);
        float wq = ((q >> 1) ? dy : 1.f - dy) * ((q & 1) ? dx : 1.f - dx);
        w4[q] = vld ? wq * msk : 0.f;
        a4[q] = ((b * H + yc) * W + xc) << 8;     // *256, c added at load
      }
    }
    #pragma unroll
    for (int q = 0; q < 4; ++q) { swt[e][q] = w4[q]; sad[e][q] = a4[q]; }
  }

  float acc[16][4];
  #pragma unroll
  for (int m2 = 0; m2 < 16; ++m2)
    #pragma unroll
    for (int nn = 0; nn < 4; ++nn) acc[m2][nn] = 0.f;

  __syncthreads();

  const int cl = t & 127, phalf = t >> 7;
  const int olane = (t & 15) << 4;      // o base: 16 contiguous o per thread
  const int nb = (t >> 4) << 2;         // 4 pixels per thread

  for (int ch = 0; ch < 18; ++ch) {
    const int k = ch >> 1;
    const int c0 = (ch & 1) << 7;
    // Phase B1: sample 128c x 64p into LDS (coalesced over c thanks to NHWC)
    const float* xp = xt + c0 + cl;
    #pragma unroll 2
    for (int it = 0; it < 32; ++it) {
      int pl = (it << 1) + phalf;
      int e = pl * 9 + k;
      float s = swt[e][0] * xp[sad[e][0]] + swt[e][1] * xp[sad[e][1]]
              + swt[e][2] * xp[sad[e][2]] + swt[e][3] * xp[sad[e][3]];
      S[pl][cl] = s;
    }
    __syncthreads();
    // Phase C: 128 x (16o x 4n) FMAs
    const float* wk = wt + (((size_t)(k << 8) + c0) << 8) + olane;
    for (int c = 0; c < 128; ++c) {
      const float* wr = wk + ((size_t)c << 8);
      float wv[16];
      *(float4*)(wv)      = *(const float4*)(wr);
      *(float4*)(wv + 4)  = *(const float4*)(wr + 4);
      *(float4*)(wv + 8)  = *(const float4*)(wr + 8);
      *(float4*)(wv + 12) = *(const float4*)(wr + 12);
      float sv[4] = {S[nb][c], S[nb + 1][c], S[nb + 2][c], S[nb + 3][c]};
      #pragma unroll
      for (int m2 = 0; m2 < 16; ++m2)
        #pragma unroll
        for (int nn = 0; nn < 4; ++nn)
          acc[m2][nn] = fmaf(wv[m2], sv[nn], acc[m2][nn]);
    }
    __syncthreads();
  }

  // epilogue: + dcn_b then bn1, write (B,256,P)
  #pragma unroll
  for (int m2 = 0; m2 < 16; ++m2) {
    int o = olane + m2;
    float al = g1[h * 256 + o] * rsqrtf(v1[h * 256 + o] + EPSBN);
    float be = (dcn_b[h * 256 + o] - m1[h * 256 + o]) * al + b1[h * 256 + o];
    #pragma unroll
    for (int nn = 0; nn < 4; ++nn) {
      int p = p0 + nb + nn;
      if (p < P) outp[(size_t)o * P + p] = fmaf(acc[m2][nn], al, be);
    }
  }
}

// ---------------- depthwise xcorr: 18x18 over 30x30 -> 13x13 ----------------
__global__ __launch_bounds__(192) void k_xcorr(float* __restrict__ ws) {
  int bc = blockIdx.x;      // b*256 + c
  int br = blockIdx.y;      // 0: cls, 1: reg
  __shared__ float ex_s[324];
  __shared__ float in_s[900];
  const float* exb = ws + (br ? HOUT2 : HOUT0) + (size_t)bc * 324;
  const float* inb = ws + (br ? HOUT3 : HOUT1) + (size_t)bc * 900;
  int t = threadIdx.x;
  for (int idx = t; idx < 324; idx += 192) ex_s[idx] = exb[idx];
  for (int idx = t; idx < 900; idx += 192) in_s[idx] = inb[idx];
  __syncthreads();
  if (t < 169) {
    int i = t / 13, j = t - (t / 13) * 13;
    float acc = 0.f;
    for (int u = 0; u < 18; ++u) {
      const float* ir = in_s + (i + u) * 30 + j;
      const float* er = ex_s + u * 18;
      #pragma unroll 6
      for (int v = 0; v < 18; ++v) acc = fmaf(ir[v], er[v], acc);
    }
    ws[XCB + ((size_t)br * 4096 + bc) * 169 + t] = acc;
  }
}

// ---------------- fuse (1x1 conv + bn2 + relu) + final projection ----------------
__global__ __launch_bounds__(256) void k_fuse(float* __restrict__ ws,
                                              const float* __restrict__ fus_b,
                                              const float* __restrict__ g2,
                                              const float* __restrict__ b2,
                                              const float* __restrict__ m2,
                                              const float* __restrict__ v2,
                                              const float* __restrict__ ow,
                                              const float* __restrict__ ob,
                                              float* __restrict__ out,
                                              int n_out, int br) {
  int ij = blockIdx.x, b = blockIdx.y;
  int t = threadIdx.x;
  __shared__ float xv[256];
  __shared__ float fv[256];
  xv[t] = ws[XCB + ((size_t)br * 4096 + b * 256 + t) * 169 + ij];
  __syncthreads();
  const float* fwt = ws + FWT + ((size_t)br << 16);
  float acc = 0.f;
  for (int c = 0; c < 256; ++c) acc = fmaf(fwt[(c << 8) + t], xv[c], acc);
  float s2 = g2[t] * rsqrtf(v2[t] + EPSBN);
  float f = (acc + fus_b[t] - m2[t]) * s2 + b2[t];
  fv[t] = fmaxf(f, 0.f);
  __syncthreads();
  int w = t >> 6, lane = t & 63;
  for (int po = w; po < n_out; po += 4) {
    float part = 0.f;
    #pragma unroll
    for (int q = 0; q < 4; ++q)
      part += ow[(po << 8) + lane + (q << 6)] * fv[lane + (q << 6)];
    for (int off = 32; off; off >>= 1) part += __shfl_down(part, off);
    if (lane == 0) out[((size_t)b * n_out + po) * 169 + ij] = part + ob[po];
  }
}

extern "C" void kernel_launch(void* const* d_in, const int* in_sizes, int n_in,
                              void* d_out, int out_size, void* d_ws, size_t ws_size,
                              hipStream_t stream) {
  const float* ex    = (const float*)d_in[0];
  const float* inst  = (const float*)d_in[1];
  const float* off_w = (const float*)d_in[2];
  const float* off_b = (const float*)d_in[3];
  const float* dcn_w = (const float*)d_in[4];
  const float* dcn_b = (const float*)d_in[5];
  const float* bn1_g = (const float*)d_in[6];
  const float* bn1_b = (const float*)d_in[7];
  const float* bn1_m = (const float*)d_in[8];
  const float* bn1_v = (const float*)d_in[9];
  const float* fus_w = (const float*)d_in[10];
  const float* fus_b = (const float*)d_in[11];
  const float* bn2_g = (const float*)d_in[12];
  const float* bn2_b = (const float*)d_in[13];
  const float* bn2_m = (const float*)d_in[14];
  const float* bn2_v = (const float*)d_in[15];
  const float* cls_w = (const float*)d_in[16];
  const float* cls_b = (const float*)d_in[17];
  const float* box_w = (const float*)d_in[18];
  const float* box_b = (const float*)d_in[19];
  float* out = (float*)d_out;
  float* ws  = (float*)d_ws;

  k_transpose<<<dim3(20, 16), 256, 0, stream>>>(ex,   ws + EX_T, 20, 20);
  k_transpose<<<dim3(32, 16), 256, 0, stream>>>(inst, ws + IN_T, 32, 32);
  k_wt <<<9216, 256, 0, stream>>>(dcn_w, ws + WT2);
  k_fwt<<<512, 256, 0, stream>>>(fus_w, ws + FWT);
  k_offconv<<<dim3(30, 4, 64), dim3(32, 8), 0, stream>>>(ex, inst, off_w, off_b, ws);
  k_dgemm<<<dim3(15, 16, 4), 256, 0, stream>>>(ws, dcn_b, bn1_g, bn1_b, bn1_m, bn1_v);
  k_xcorr<<<dim3(4096, 2), 192, 0, stream>>>(ws);
  k_fuse<<<dim3(169, 16), 256, 0, stream>>>(ws, fus_b, bn2_g, bn2_b, bn2_m, bn2_v,
                                            cls_w, cls_b, out, 4, 0);
  k_fuse<<<dim3(169, 16), 256, 0, stream>>>(ws, fus_b + 256, bn2_g + 256, bn2_b + 256,
                                            bn2_m + 256, bn2_v + 256, box_w, box_b,
                                            out + 10816, 16, 1);
}

// Round 4
// 395.321 us; speedup vs baseline: 7.2132x; 7.2132x over previous
//
#include <hip/hip_runtime.h>
#include <math.h>

#define EPSBN 1e-5f

typedef _Float16 f16x8 __attribute__((ext_vector_type(8)));
typedef float    f32x4 __attribute__((ext_vector_type(4)));

__device__ __forceinline__ f16x8 splat8(float v) {
  _Float16 h = (_Float16)v;
  return (f16x8){h, h, h, h, h, h, h, h};
}

// ---------------- workspace layout (float-unit offsets) ----------------
static constexpr size_t XF_EX = 0;         // (16,20,20,256) f16  -> 819200 floats
static constexpr size_t XF_IN = 819200;    // (16,32,32,256) f16  -> 2097152 floats
static constexpr size_t WPK   = 2916352;   // dcn_w f16 frag pack -> 1179648 floats
static constexpr size_t OWPK  = 4096000;   // off_w f16 frag pack -> 147456 floats
static constexpr size_t FWT   = 4243456;   // (2,256,256) f32     -> 131072
static constexpr size_t OM0   = 4374528;   // (16,27,324)
static constexpr size_t OM1   = 4514496;   // (16,27,900)
static constexpr size_t OM2   = 4903296;
static constexpr size_t OM3   = 5043264;
static constexpr size_t HOUT0 = 5432064;   // (16,256,324) f32
static constexpr size_t HOUT1 = 6759168;   // (16,256,900) f32
static constexpr size_t HOUT2 = 10445568;
static constexpr size_t HOUT3 = 11772672;
static constexpr size_t XCB   = 15459072;  // (2,16,256,169) f32
// end 18227968 floats = 72.9 MB

// ---------------- NCHW fp32 -> NHWC f16 ----------------
__global__ __launch_bounds__(256) void k_transpose(const float* __restrict__ in,
                                                   _Float16* __restrict__ out,
                                                   int H, int W) {
  int y = blockIdx.x, b = blockIdx.y;
  __shared__ float tile[32][257];
  int t = threadIdx.x;
  int x = t & 31, cb = t >> 5;
  for (int c0 = 0; c0 < 256; c0 += 8) {
    int c = c0 + cb;
    if (x < W) tile[x][c] = in[(((size_t)b * 256 + c) * H + y) * W + x];
  }
  __syncthreads();
  for (int x2 = 0; x2 < W; ++x2)
    out[((((size_t)b * H + y) * W + x2) << 8) + t] = (_Float16)tile[x2][t];
}

// ---------------- dcn_w -> f16 MFMA-A fragment pack ----------------
// layout: ((((h*9+tap)*8+cs)*16+ot)*64+lane)*8+e ; o=ot*16+(lane&15), c=cs*32+8*(lane>>4)+e
__global__ __launch_bounds__(256) void k_wpack(const float* __restrict__ w,
                                               _Float16* __restrict__ wp) {
  int idx = blockIdx.x * 256 + threadIdx.x;
  if (idx >= 4 * 9 * 8 * 16 * 64 * 8) return;
  int e  = idx & 7;
  int l  = (idx >> 3) & 63;
  int ot = (idx >> 9) & 15;
  int cs = (idx >> 13) & 7;
  int ht = idx >> 16;             // h*9 + tap
  int tap = ht % 9, h = ht / 9;
  int o = ot * 16 + (l & 15);
  int c = cs * 32 + 8 * (l >> 4) + e;
  wp[idx] = (_Float16)w[((size_t)((h * 256 + o) * 256 + c)) * 9 + tap];
}

// ---------------- off_w -> f16 MFMA-A fragment pack (M=27 padded to 32) ----------------
// layout: ((((h*9+tap)*8+cs)*2+ot)*64+lane)*8+e
__global__ __launch_bounds__(256) void k_owpack(const float* __restrict__ w,
                                                _Float16* __restrict__ wp) {
  int idx = blockIdx.x * 256 + threadIdx.x;
  if (idx >= 4 * 9 * 8 * 2 * 64 * 8) return;
  int e  = idx & 7;
  int l  = (idx >> 3) & 63;
  int ot = (idx >> 9) & 1;
  int cs = (idx >> 10) & 7;
  int ht = idx >> 13;
  int tap = ht % 9, h = ht / 9;
  int o = ot * 16 + (l & 15);
  int c = cs * 32 + 8 * (l >> 4) + e;
  wp[idx] = (o < 27) ? (_Float16)w[((size_t)((h * 27 + o) * 256 + c)) * 9 + tap]
                     : (_Float16)0.f;
}

// ---------------- fus_w (2,256,256)[i][o][c] -> fwt [i][c][o] (fp32) ----------------
__global__ __launch_bounds__(256) void k_fwt(const float* __restrict__ w,
                                             float* __restrict__ wt) {
  int idx = blockIdx.x * 256 + threadIdx.x;
  int o = idx & 255, c = (idx >> 8) & 255, i = idx >> 16;
  wt[idx] = w[(i << 16) + (o << 8) + c];
}

// ---------------- offset conv via MFMA (M=32 pad of 27, K=2304, N=64p tile) ----------------
__global__ __launch_bounds__(256) void k_offmfma(const _Float16* __restrict__ xh_ex,
                                                 const _Float16* __restrict__ xh_in,
                                                 const _Float16* __restrict__ owpk,
                                                 const float* __restrict__ off_b,
                                                 float* __restrict__ ws) {
  const int h = blockIdx.z, b = blockIdx.y;
  const int HH[4] = {20, 32, 20, 32};
  const size_t OMO[4] = {OM0, OM1, OM2, OM3};
  const int H = HH[h], W = H, ho = H - 2, wo = W - 2, P = ho * wo;
  const int nblk = (P + 63) >> 6;
  if (blockIdx.x >= nblk) return;
  const int p0 = blockIdx.x << 6;
  const _Float16* xh = ((h & 1) ? xh_in : xh_ex) + (((size_t)b * H * W) << 8);

  __shared__ __align__(16) _Float16 S[64 * 256];
  __shared__ int rowoff[64];

  const int t = threadIdx.x, lane = t & 63, wave = t >> 6;
  if (t < 64) {
    int p = min(p0 + t, P - 1);
    int i = p / wo, j = p - i * wo;
    rowoff[t] = (i * W + j) << 8;
  }
  f32x4 acc0 = {0.f, 0.f, 0.f, 0.f}, acc1 = {0.f, 0.f, 0.f, 0.f};
  __syncthreads();

  const int o8 = t & 31;
  for (int tap = 0; tap < 9; ++tap) {
    const int ky = tap / 3, kx = tap - ky * 3;
    const int koff = (ky * W + kx) << 8;
    #pragma unroll
    for (int it = 0; it < 8; ++it) {
      int pl = it * 8 + (t >> 5);
      f16x8 v = *(const f16x8*)(xh + rowoff[pl] + koff + o8 * 8);
      *(f16x8*)((char*)S + pl * 512 + ((o8 * 16) ^ ((pl & 7) << 4))) = v;
    }
    __syncthreads();
    #pragma unroll
    for (int cs = 0; cs < 8; ++cs) {
      int ksg = tap * 8 + cs;
      const _Float16* ab = owpk + ((size_t)(h * 72 + ksg) * 2) * 512 + lane * 8;
      f16x8 a0 = *(const f16x8*)(ab);
      f16x8 a1 = *(const f16x8*)(ab + 512);
      int prow = wave * 16 + (lane & 15);
      f16x8 bf = *(const f16x8*)((char*)S + prow * 512 +
                                 ((cs * 64 + ((lane >> 4) << 4)) ^ ((prow & 7) << 4)));
      acc0 = __builtin_amdgcn_mfma_f32_16x16x32_f16(a0, bf, acc0, 0, 0, 0);
      acc1 = __builtin_amdgcn_mfma_f32_16x16x32_f16(a1, bf, acc1, 0, 0, 0);
    }
    __syncthreads();
  }
  float* om = ws + OMO[h] + (size_t)b * 27 * P;
  int p = p0 + wave * 16 + (lane & 15);
  if (p < P) {
    #pragma unroll
    for (int r = 0; r < 4; ++r) {
      int o = 4 * (lane >> 4) + r;
      if (o < 27) om[o * P + p] = acc0[r] + off_b[h * 27 + o];
      int o2 = o + 16;
      if (o2 < 27) om[o2 * P + p] = acc1[r] + off_b[h * 27 + o2];
    }
  }
}

// ---------------- main deformable GEMM on MFMA, bn1 folded ----------------
// block: 256 thr (4 waves); tile 256o x 64p; K = 9 taps x 256c
__global__ __launch_bounds__(256) void k_dgemm(const _Float16* __restrict__ xh_ex,
                                               const _Float16* __restrict__ xh_in,
                                               const _Float16* __restrict__ wpk,
                                               float* __restrict__ ws,
                                               const float* __restrict__ dcn_b,
                                               const float* __restrict__ g1,
                                               const float* __restrict__ b1,
                                               const float* __restrict__ m1,
                                               const float* __restrict__ v1) {
  const int h = blockIdx.z;
  const int HH4[4] = {20, 32, 20, 32};
  const size_t OMO[4] = {OM0, OM1, OM2, OM3};
  const size_t HOO[4] = {HOUT0, HOUT1, HOUT2, HOUT3};
  const int H = HH4[h], W = H, ho = H - 2, wo = W - 2, P = ho * wo;
  const int nblk = (P + 63) >> 6;
  if (blockIdx.x >= nblk) return;
  const int b = blockIdx.y;
  const int p0 = blockIdx.x << 6;
  const _Float16* xh = (h & 1) ? xh_in : xh_ex;
  const float* om = ws + OMO[h] + (size_t)b * 27 * P;
  float* outp = ws + HOO[h] + (size_t)b * 256 * P;

  __shared__ float4 swt4[576];
  __shared__ int4   sad4[576];
  __shared__ __align__(16) _Float16 S[64 * 256];

  const int t = threadIdx.x, lane = t & 63, wave = t >> 6;

  // Phase A: per-(pixel,tap) bilinear weights (mask+validity folded) & base addrs
  for (int e = t; e < 576; e += 256) {
    int pl = e / 9, k = e - pl * 9;
    float w4[4] = {0.f, 0.f, 0.f, 0.f};
    int a4[4] = {0, 0, 0, 0};
    int p = p0 + pl;
    if (p < P) {
      int i = p / wo, j = p - i * wo;
      float oy = om[(2 * k) * P + p];
      float ox = om[(2 * k + 1) * P + p];
      float mm = om[(18 + k) * P + p];
      float msk = 1.f / (1.f + __expf(-mm));
      int ky = k / 3, kx = k - ky * 3;
      float py = (float)(ky + i) + oy;
      float px = (float)(kx + j) + ox;
      float fy = floorf(py), fx = floorf(px);
      int y0 = (int)fy, x0 = (int)fx;
      float dy = py - fy, dx = px - fx;
      #pragma unroll
      for (int q = 0; q < 4; ++q) {
        int yy = y0 + (q >> 1), xx = x0 + (q & 1);
        bool vld = (yy >= 0) && (yy < H) && (xx >= 0) && (xx < W);
        int yc = min(max(yy, 0), H - 1), xc = min(max(xx, 0), W - 1);
        float wq = ((q >> 1) ? dy : 1.f - dy) * ((q & 1) ? dx : 1.f - dx);
        w4[q] = vld ? wq * msk : 0.f;
        a4[q] = ((blockIdx.y * H + yc) * W + xc) << 8;    // element index, c added later
      }
    }
    swt4[e] = make_float4(w4[0], w4[1], w4[2], w4[3]);
    sad4[e] = make_int4(a4[0], a4[1], a4[2], a4[3]);
  }

  f32x4 acc[4][4];
  #pragma unroll
  for (int a = 0; a < 4; ++a)
    #pragma unroll
    for (int n = 0; n < 4; ++n) acc[a][n] = (f32x4){0.f, 0.f, 0.f, 0.f};

  __syncthreads();

  const int o8 = t & 31;
  for (int tap = 0; tap < 9; ++tap) {
    // Phase B: sample 64p x 256c f16 into swizzled LDS
    #pragma unroll
    for (int it = 0; it < 8; ++it) {
      int pl = it * 8 + (t >> 5);
      float4 w4 = swt4[pl * 9 + tap];
      int4   a4 = sad4[pl * 9 + tap];
      const _Float16* xb = xh + o8 * 8;
      f16x8 x0 = *(const f16x8*)(xb + a4.x);
      f16x8 x1 = *(const f16x8*)(xb + a4.y);
      f16x8 x2 = *(const f16x8*)(xb + a4.z);
      f16x8 x3 = *(const f16x8*)(xb + a4.w);
      f16x8 s = x0 * splat8(w4.x) + x1 * splat8(w4.y) + x2 * splat8(w4.z) + x3 * splat8(w4.w);
      *(f16x8*)((char*)S + pl * 512 + ((o8 * 16) ^ ((pl & 7) << 4))) = s;
    }
    __syncthreads();
    // Phase C: 8 K-steps x (4 otile x 4 ptile) MFMA
    #pragma unroll
    for (int cs = 0; cs < 8; ++cs) {
      int ksg = tap * 8 + cs;
      const _Float16* ab = wpk + ((size_t)(h * 72 + ksg) * 16 + wave * 4) * 512 + lane * 8;
      f16x8 A0 = *(const f16x8*)(ab);
      f16x8 A1 = *(const f16x8*)(ab + 512);
      f16x8 A2 = *(const f16x8*)(ab + 1024);
      f16x8 A3 = *(const f16x8*)(ab + 1536);
      f16x8 B[4];
      #pragma unroll
      for (int n = 0; n < 4; ++n) {
        int prow = n * 16 + (lane & 15);
        B[n] = *(const f16x8*)((char*)S + prow * 512 +
                               ((cs * 64 + ((lane >> 4) << 4)) ^ ((prow & 7) << 4)));
      }
      #pragma unroll
      for (int n = 0; n < 4; ++n) {
        acc[0][n] = __builtin_amdgcn_mfma_f32_16x16x32_f16(A0, B[n], acc[0][n], 0, 0, 0);
        acc[1][n] = __builtin_amdgcn_mfma_f32_16x16x32_f16(A1, B[n], acc[1][n], 0, 0, 0);
        acc[2][n] = __builtin_amdgcn_mfma_f32_16x16x32_f16(A2, B[n], acc[2][n], 0, 0, 0);
        acc[3][n] = __builtin_amdgcn_mfma_f32_16x16x32_f16(A3, B[n], acc[3][n], 0, 0, 0);
      }
    }
    __syncthreads();
  }

  // epilogue: + dcn_b then bn1; out layout (B,256o,P)
  #pragma unroll
  for (int a = 0; a < 4; ++a) {
    int obase = (wave * 4 + a) * 16 + 4 * (lane >> 4);
    #pragma unroll
    for (int r = 0; r < 4; ++r) {
      int o = obase + r;
      float al = g1[h * 256 + o] * rsqrtf(v1[h * 256 + o] + EPSBN);
      float be = (dcn_b[h * 256 + o] - m1[h * 256 + o]) * al + b1[h * 256 + o];
      #pragma unroll
      for (int n = 0; n < 4; ++n) {
        int p = p0 + n * 16 + (lane & 15);
        if (p < P) outp[(size_t)o * P + p] = fmaf(acc[a][n][r], al, be);
      }
    }
  }
}

// ---------------- depthwise xcorr: 18x18 over 30x30 -> 13x13 ----------------
__global__ __launch_bounds__(192) void k_xcorr(float* __restrict__ ws) {
  int bc = blockIdx.x;
  int br = blockIdx.y;
  __shared__ float ex_s[324];
  __shared__ float in_s[900];
  const float* exb = ws + (br ? HOUT2 : HOUT0) + (size_t)bc * 324;
  const float* inb = ws + (br ? HOUT3 : HOUT1) + (size_t)bc * 900;
  int t = threadIdx.x;
  for (int idx = t; idx < 324; idx += 192) ex_s[idx] = exb[idx];
  for (int idx = t; idx < 900; idx += 192) in_s[idx] = inb[idx];
  __syncthreads();
  if (t < 169) {
    int i = t / 13, j = t - (t / 13) * 13;
    float acc = 0.f;
    for (int u = 0; u < 18; ++u) {
      const float* ir = in_s + (i + u) * 30 + j;
      const float* er = ex_s + u * 18;
      #pragma unroll 6
      for (int v = 0; v < 18; ++v) acc = fmaf(ir[v], er[v], acc);
    }
    ws[XCB + ((size_t)br * 4096 + bc) * 169 + t] = acc;
  }
}

// ---------------- fuse (1x1 conv + bn2 + relu) + final projection ----------------
__global__ __launch_bounds__(256) void k_fuse(float* __restrict__ ws,
                                              const float* __restrict__ fus_b,
                                              const float* __restrict__ g2,
                                              const float* __restrict__ b2,
                                              const float* __restrict__ m2,
                                              const float* __restrict__ v2,
                                              const float* __restrict__ ow,
                                              const float* __restrict__ ob,
                                              float* __restrict__ out,
                                              int n_out, int br) {
  int ij = blockIdx.x, b = blockIdx.y;
  int t = threadIdx.x;
  __shared__ float xv[256];
  __shared__ float fv[256];
  xv[t] = ws[XCB + ((size_t)br * 4096 + b * 256 + t) * 169 + ij];
  __syncthreads();
  const float* fwt = ws + FWT + ((size_t)br << 16);
  float acc = 0.f;
  for (int c = 0; c < 256; ++c) acc = fmaf(fwt[(c << 8) + t], xv[c], acc);
  float s2 = g2[t] * rsqrtf(v2[t] + EPSBN);
  float f = (acc + fus_b[t] - m2[t]) * s2 + b2[t];
  fv[t] = fmaxf(f, 0.f);
  __syncthreads();
  int w = t >> 6, lane = t & 63;
  for (int po = w; po < n_out; po += 4) {
    float part = 0.f;
    #pragma unroll
    for (int q = 0; q < 4; ++q)
      part += ow[(po << 8) + lane + (q << 6)] * fv[lane + (q << 6)];
    for (int off = 32; off; off >>= 1) part += __shfl_down(part, off);
    if (lane == 0) out[((size_t)b * n_out + po) * 169 + ij] = part + ob[po];
  }
}

extern "C" void kernel_launch(void* const* d_in, const int* in_sizes, int n_in,
                              void* d_out, int out_size, void* d_ws, size_t ws_size,
                              hipStream_t stream) {
  const float* ex    = (const float*)d_in[0];
  const float* inst  = (const float*)d_in[1];
  const float* off_w = (const float*)d_in[2];
  const float* off_b = (const float*)d_in[3];
  const float* dcn_w = (const float*)d_in[4];
  const float* dcn_b = (const float*)d_in[5];
  const float* bn1_g = (const float*)d_in[6];
  const float* bn1_b = (const float*)d_in[7];
  const float* bn1_m = (const float*)d_in[8];
  const float* bn1_v = (const float*)d_in[9];
  const float* fus_w = (const float*)d_in[10];
  const float* fus_b = (const float*)d_in[11];
  const float* bn2_g = (const float*)d_in[12];
  const float* bn2_b = (const float*)d_in[13];
  const float* bn2_m = (const float*)d_in[14];
  const float* bn2_v = (const float*)d_in[15];
  const float* cls_w = (const float*)d_in[16];
  const float* cls_b = (const float*)d_in[17];
  const float* box_w = (const float*)d_in[18];
  const float* box_b = (const float*)d_in[19];
  float* out = (float*)d_out;
  float* ws  = (float*)d_ws;

  _Float16* xh_ex = (_Float16*)(ws + XF_EX);
  _Float16* xh_in = (_Float16*)(ws + XF_IN);
  _Float16* wpk   = (_Float16*)(ws + WPK);
  _Float16* owpk  = (_Float16*)(ws + OWPK);

  k_transpose<<<dim3(20, 16), 256, 0, stream>>>(ex,   xh_ex, 20, 20);
  k_transpose<<<dim3(32, 16), 256, 0, stream>>>(inst, xh_in, 32, 32);
  k_wpack <<<9216, 256, 0, stream>>>(dcn_w, wpk);
  k_owpack<<<1152, 256, 0, stream>>>(off_w, owpk);
  k_fwt   <<<512, 256, 0, stream>>>(fus_w, ws + FWT);
  k_offmfma<<<dim3(15, 16, 4), 256, 0, stream>>>(xh_ex, xh_in, owpk, off_b, ws);
  k_dgemm<<<dim3(15, 16, 4), 256, 0, stream>>>(xh_ex, xh_in, wpk, ws,
                                               dcn_b, bn1_g, bn1_b, bn1_m, bn1_v);
  k_xcorr<<<dim3(4096, 2), 192, 0, stream>>>(ws);
  k_fuse<<<dim3(169, 16), 256, 0, stream>>>(ws, fus_b, bn2_g, bn2_b, bn2_m, bn2_v,
                                            cls_w, cls_b, out, 4, 0);
  k_fuse<<<dim3(169, 16), 256, 0, stream>>>(ws, fus_b + 256, bn2_g + 256, bn2_b + 256,
                                            bn2_m + 256, bn2_v + 256, box_w, box_b,
                                            out + 10816, 16, 1);
}

// Round 7
// 338.073 us; speedup vs baseline: 8.4347x; 1.1693x over previous
//
#include <hip/hip_runtime.h>
#include <math.h>

#define EPSBN 1e-5f

typedef _Float16 f16x8 __attribute__((ext_vector_type(8)));
typedef _Float16 f16x2 __attribute__((ext_vector_type(2)));
typedef float    f32x4 __attribute__((ext_vector_type(4)));

__device__ __forceinline__ f16x8 splat8(float v) {
  _Float16 h = (_Float16)v;
  return (f16x8){h, h, h, h, h, h, h, h};
}

// ---------------- workspace layout (float-unit offsets) — round-4 validated ----
static constexpr size_t XF_EX = 0;         // (16,20,20,256) f16
static constexpr size_t XF_IN = 819200;    // (16,32,32,256) f16
static constexpr size_t WPK   = 2916352;   // dcn_w f16 frag pack
static constexpr size_t OWPK  = 4096000;   // off_w f16 frag pack
static constexpr size_t FWT   = 4243456;   // (2,256,256) f32
static constexpr size_t OM0   = 4374528;   // (16,27,324) f32
static constexpr size_t OM1   = 4514496;   // (16,27,900)
static constexpr size_t OM2   = 4903296;
static constexpr size_t OM3   = 5043264;
static constexpr size_t HOUT0 = 5432064;   // (16,256,324) f32
static constexpr size_t HOUT1 = 6759168;   // (16,256,900) f32
static constexpr size_t HOUT2 = 10445568;
static constexpr size_t HOUT3 = 11772672;
static constexpr size_t XCB   = 15459072;  // (2,16,256,169) f32
// end 18227968 floats = 72.9 MB

// ---------------- NCHW fp32 -> NHWC f16 ----------------
__global__ __launch_bounds__(256) void k_transpose(const float* __restrict__ in,
                                                   _Float16* __restrict__ out,
                                                   int H, int W) {
  int y = blockIdx.x, b = blockIdx.y;
  __shared__ float tile[32][257];
  int t = threadIdx.x;
  int x = t & 31, cb = t >> 5;
  for (int c0 = 0; c0 < 256; c0 += 8) {
    int c = c0 + cb;
    if (x < W) tile[x][c] = in[(((size_t)b * 256 + c) * H + y) * W + x];
  }
  __syncthreads();
  for (int x2 = 0; x2 < W; ++x2)
    out[((((size_t)b * H + y) * W + x2) << 8) + t] = (_Float16)tile[x2][t];
}

// ---------------- dcn_w -> f16 MFMA-A fragment pack (round-4 validated) -------
// layout: ((((h*9+tap)*8+cs)*16+ot)*64+lane)*8+e ; o=ot*16+(lane&15), c=cs*32+8*(lane>>4)+e
__global__ __launch_bounds__(256) void k_wpack(const float* __restrict__ w,
                                               _Float16* __restrict__ wp) {
  int idx = blockIdx.x * 256 + threadIdx.x;
  if (idx >= 4 * 9 * 8 * 16 * 64 * 8) return;
  int e  = idx & 7;
  int l  = (idx >> 3) & 63;
  int ot = (idx >> 9) & 15;
  int cs = (idx >> 13) & 7;
  int ht = idx >> 16;             // h*9 + tap
  int tap = ht % 9, h = ht / 9;
  int o = ot * 16 + (l & 15);
  int c = cs * 32 + 8 * (l >> 4) + e;
  wp[idx] = (_Float16)w[((size_t)((h * 256 + o) * 256 + c)) * 9 + tap];
}

// ---------------- off_w -> f16 MFMA-A fragment pack (M=27 padded to 32) -------
__global__ __launch_bounds__(256) void k_owpack(const float* __restrict__ w,
                                                _Float16* __restrict__ wp) {
  int idx = blockIdx.x * 256 + threadIdx.x;
  if (idx >= 4 * 9 * 8 * 2 * 64 * 8) return;
  int e  = idx & 7;
  int l  = (idx >> 3) & 63;
  int ot = (idx >> 9) & 1;
  int cs = (idx >> 10) & 7;
  int ht = idx >> 13;
  int tap = ht % 9, h = ht / 9;
  int o = ot * 16 + (l & 15);
  int c = cs * 32 + 8 * (l >> 4) + e;
  wp[idx] = (o < 27) ? (_Float16)w[((size_t)((h * 27 + o) * 256 + c)) * 9 + tap]
                     : (_Float16)0.f;
}

// ---------------- fus_w (2,256,256)[i][o][c] -> fwt [i][c][o] (fp32) ----------
__global__ __launch_bounds__(256) void k_fwt(const float* __restrict__ w,
                                             float* __restrict__ wt) {
  int idx = blockIdx.x * 256 + threadIdx.x;
  int o = idx & 255, c = (idx >> 8) & 255, i = idx >> 16;
  wt[idx] = w[(i << 16) + (o << 8) + c];
}

// ---------------- offset conv via MFMA (M=32 pad of 27, K=2304, N=64p) --------
__global__ __launch_bounds__(256) void k_offmfma(const _Float16* __restrict__ xh_ex,
                                                 const _Float16* __restrict__ xh_in,
                                                 const _Float16* __restrict__ owpk,
                                                 const float* __restrict__ off_b,
                                                 float* __restrict__ ws) {
  const int h = blockIdx.z, b = blockIdx.y;
  const int HH[4] = {20, 32, 20, 32};
  const size_t OMO[4] = {OM0, OM1, OM2, OM3};
  const int H = HH[h], W = H, ho = H - 2, wo = W - 2, P = ho * wo;
  const int nblk = (P + 63) >> 6;
  if (blockIdx.x >= nblk) return;
  const int p0 = blockIdx.x << 6;
  const _Float16* xh = ((h & 1) ? xh_in : xh_ex) + (((size_t)b * H * W) << 8);

  __shared__ __align__(16) _Float16 S[64 * 256];
  __shared__ int rowoff[64];

  const int t = threadIdx.x, lane = t & 63, wave = t >> 6;
  if (t < 64) {
    int p = min(p0 + t, P - 1);
    int i = p / wo, j = p - i * wo;
    rowoff[t] = (i * W + j) << 8;
  }
  f32x4 acc0 = {0.f, 0.f, 0.f, 0.f}, acc1 = {0.f, 0.f, 0.f, 0.f};
  __syncthreads();

  const int o8 = t & 31;
  for (int tap = 0; tap < 9; ++tap) {
    const int ky = tap / 3, kx = tap - ky * 3;
    const int koff = (ky * W + kx) << 8;
    #pragma unroll
    for (int it = 0; it < 8; ++it) {
      int pl = it * 8 + (t >> 5);
      f16x8 v = *(const f16x8*)(xh + rowoff[pl] + koff + o8 * 8);
      *(f16x8*)((char*)S + pl * 512 + ((o8 * 16) ^ ((pl & 7) << 4))) = v;
    }
    __syncthreads();
    #pragma unroll
    for (int cs = 0; cs < 8; ++cs) {
      int ksg = tap * 8 + cs;
      const _Float16* ab = owpk + ((size_t)(h * 72 + ksg) * 2) * 512 + lane * 8;
      f16x8 a0 = *(const f16x8*)(ab);
      f16x8 a1 = *(const f16x8*)(ab + 512);
      int prow = wave * 16 + (lane & 15);
      f16x8 bf = *(const f16x8*)((char*)S + prow * 512 +
                                 ((cs * 64 + ((lane >> 4) << 4)) ^ ((prow & 7) << 4)));
      acc0 = __builtin_amdgcn_mfma_f32_16x16x32_f16(a0, bf, acc0, 0, 0, 0);
      acc1 = __builtin_amdgcn_mfma_f32_16x16x32_f16(a1, bf, acc1, 0, 0, 0);
    }
    __syncthreads();
  }
  float* om = ws + OMO[h] + (size_t)b * 27 * P;
  int p = p0 + wave * 16 + (lane & 15);
  if (p < P) {
    #pragma unroll
    for (int r = 0; r < 4; ++r) {
      int o = 4 * (lane >> 4) + r;
      if (o < 27) om[o * P + p] = acc0[r] + off_b[h * 27 + o];
      int o2 = o + 16;
      if (o2 < 27) om[o2 * P + p] = acc1[r] + off_b[h * 27 + o2];
    }
  }
}

// ---------------- main deformable GEMM on MFMA, bn1 folded (round-4 epilogue) --
__global__ __launch_bounds__(256) void k_dgemm(const _Float16* __restrict__ xh_ex,
                                               const _Float16* __restrict__ xh_in,
                                               const _Float16* __restrict__ wpk,
                                               float* __restrict__ ws,
                                               const float* __restrict__ dcn_b,
                                               const float* __restrict__ g1,
                                               const float* __restrict__ b1,
                                               const float* __restrict__ m1,
                                               const float* __restrict__ v1) {
  const int h = blockIdx.z;
  const int HH4[4] = {20, 32, 20, 32};
  const size_t OMO[4] = {OM0, OM1, OM2, OM3};
  const size_t HOO[4] = {HOUT0, HOUT1, HOUT2, HOUT3};
  const int H = HH4[h], W = H, ho = H - 2, wo = W - 2, P = ho * wo;
  const int nblk = (P + 63) >> 6;
  if (blockIdx.x >= nblk) return;
  const int b = blockIdx.y;
  const int p0 = blockIdx.x << 6;
  const _Float16* xh = (h & 1) ? xh_in : xh_ex;
  const float* om = ws + OMO[h] + (size_t)b * 27 * P;
  float* outp = ws + HOO[h] + (size_t)b * 256 * P;

  __shared__ float4 swt4[576];
  __shared__ int4   sad4[576];
  __shared__ __align__(16) _Float16 S[64 * 256];

  const int t = threadIdx.x, lane = t & 63, wave = t >> 6;

  // Phase A: per-(pixel,tap) bilinear weights (mask+validity folded) & base addrs
  for (int e = t; e < 576; e += 256) {
    int pl = e / 9, k = e - pl * 9;
    float w4[4] = {0.f, 0.f, 0.f, 0.f};
    int a4[4] = {0, 0, 0, 0};
    int p = p0 + pl;
    if (p < P) {
      int i = p / wo, j = p - i * wo;
      float oy = om[(2 * k) * P + p];
      float ox = om[(2 * k + 1) * P + p];
      float mm = om[(18 + k) * P + p];
      float msk = 1.f / (1.f + __expf(-mm));
      int ky = k / 3, kx = k - ky * 3;
      float py = (float)(ky + i) + oy;
      float px = (float)(kx + j) + ox;
      float fy = floorf(py), fx = floorf(px);
      int y0 = (int)fy, x0 = (int)fx;
      float dy = py - fy, dx = px - fx;
      #pragma unroll
      for (int q = 0; q < 4; ++q) {
        int yy = y0 + (q >> 1), xx = x0 + (q & 1);
        bool vld = (yy >= 0) && (yy < H) && (xx >= 0) && (xx < W);
        int yc = min(max(yy, 0), H - 1), xc = min(max(xx, 0), W - 1);
        float wq = ((q >> 1) ? dy : 1.f - dy) * ((q & 1) ? dx : 1.f - dx);
        w4[q] = vld ? wq * msk : 0.f;
        a4[q] = ((blockIdx.y * H + yc) * W + xc) << 8;
      }
    }
    swt4[e] = make_float4(w4[0], w4[1], w4[2], w4[3]);
    sad4[e] = make_int4(a4[0], a4[1], a4[2], a4[3]);
  }

  f32x4 acc[4][4];
  #pragma unroll
  for (int a = 0; a < 4; ++a)
    #pragma unroll
    for (int n = 0; n < 4; ++n) acc[a][n] = (f32x4){0.f, 0.f, 0.f, 0.f};

  __syncthreads();

  const int o8 = t & 31;
  for (int tap = 0; tap < 9; ++tap) {
    // Phase B: sample 64p x 256c f16 into swizzled LDS
    #pragma unroll
    for (int it = 0; it < 8; ++it) {
      int pl = it * 8 + (t >> 5);
      float4 w4 = swt4[pl * 9 + tap];
      int4   a4 = sad4[pl * 9 + tap];
      const _Float16* xb = xh + o8 * 8;
      f16x8 x0 = *(const f16x8*)(xb + a4.x);
      f16x8 x1 = *(const f16x8*)(xb + a4.y);
      f16x8 x2 = *(const f16x8*)(xb + a4.z);
      f16x8 x3 = *(const f16x8*)(xb + a4.w);
      f16x8 s = x0 * splat8(w4.x) + x1 * splat8(w4.y) + x2 * splat8(w4.z) + x3 * splat8(w4.w);
      *(f16x8*)((char*)S + pl * 512 + ((o8 * 16) ^ ((pl & 7) << 4))) = s;
    }
    __syncthreads();
    // Phase C: 8 K-steps x (4 otile x 4 ptile) MFMA
    #pragma unroll
    for (int cs = 0; cs < 8; ++cs) {
      int ksg = tap * 8 + cs;
      const _Float16* ab = wpk + ((size_t)(h * 72 + ksg) * 16 + wave * 4) * 512 + lane * 8;
      f16x8 A0 = *(const f16x8*)(ab);
      f16x8 A1 = *(const f16x8*)(ab + 512);
      f16x8 A2 = *(const f16x8*)(ab + 1024);
      f16x8 A3 = *(const f16x8*)(ab + 1536);
      f16x8 B[4];
      #pragma unroll
      for (int n = 0; n < 4; ++n) {
        int prow = n * 16 + (lane & 15);
        B[n] = *(const f16x8*)((char*)S + prow * 512 +
                               ((cs * 64 + ((lane >> 4) << 4)) ^ ((prow & 7) << 4)));
      }
      #pragma unroll
      for (int n = 0; n < 4; ++n) {
        acc[0][n] = __builtin_amdgcn_mfma_f32_16x16x32_f16(A0, B[n], acc[0][n], 0, 0, 0);
        acc[1][n] = __builtin_amdgcn_mfma_f32_16x16x32_f16(A1, B[n], acc[1][n], 0, 0, 0);
        acc[2][n] = __builtin_amdgcn_mfma_f32_16x16x32_f16(A2, B[n], acc[2][n], 0, 0, 0);
        acc[3][n] = __builtin_amdgcn_mfma_f32_16x16x32_f16(A3, B[n], acc[3][n], 0, 0, 0);
      }
    }
    __syncthreads();
  }

  // epilogue: + dcn_b then bn1; out layout (B,256o,P) fp32 (validated)
  #pragma unroll
  for (int a = 0; a < 4; ++a) {
    int obase = (wave * 4 + a) * 16 + 4 * (lane >> 4);
    #pragma unroll
    for (int r = 0; r < 4; ++r) {
      int o = obase + r;
      float al = g1[h * 256 + o] * rsqrtf(v1[h * 256 + o] + EPSBN);
      float be = (dcn_b[h * 256 + o] - m1[h * 256 + o]) * al + b1[h * 256 + o];
      #pragma unroll
      for (int n = 0; n < 4; ++n) {
        int p = p0 + n * 16 + (lane & 15);
        if (p < P) outp[(size_t)o * P + p] = fmaf(acc[a][n][r], al, be);
      }
    }
  }
}

// ---------------- xcorr v3: register-blocked, fp32 HOUT in, f16 LDS stage -----
// 16 bc per block; thread = (bcl, output row i); per u: 30-wide inst row to regs
// once -> 234 FMAs (static sliding window). All LDS cells explicitly written.
__global__ __launch_bounds__(256) void k_xcorr3(float* __restrict__ ws) {
  const int br = blockIdx.y;
  const int bc0 = blockIdx.x << 4;
  const float* exg = ws + (br ? HOUT2 : HOUT0) + (size_t)bc0 * 324;
  const float* ing = ws + (br ? HOUT3 : HOUT1) + (size_t)bc0 * 900;
  __shared__ __align__(16) _Float16 exl[16 * 324];
  __shared__ __align__(16) _Float16 inl[16 * 960];   // rows padded 30 -> 32
  const int t = threadIdx.x;
  for (int idx = t; idx < 16 * 324; idx += 256)
    exl[idx] = (_Float16)exg[idx];
  for (int idx = t; idx < 16 * 960; idx += 256) {
    int c = idx & 31;
    int rr = idx >> 5;                                // bcl*30 + row
    inl[idx] = (c < 30) ? (_Float16)ing[rr * 30 + c] : (_Float16)0.f;
  }
  __syncthreads();
  const int lane = t & 63, wave = t >> 6;
  const int sub = lane / 13;            // 0..3 active, 4 = idle lanes
  const int i = lane - sub * 13;
  const bool active = sub < 4;
  const int bcl = wave * 4 + (active ? sub : 0);
  float acc[13];
  #pragma unroll
  for (int j = 0; j < 13; ++j) acc[j] = 0.f;
  const _Float16* inb = inl + bcl * 960;
  const _Float16* exb = exl + bcl * 324;
  for (int u = 0; u < 18; ++u) {
    float a[30];
    const _Float16* rp = inb + (i + u) * 32;
    #pragma unroll
    for (int x = 0; x < 15; ++x) {
      f16x2 pr = *(const f16x2*)(rp + 2 * x);
      a[2 * x] = (float)pr[0]; a[2 * x + 1] = (float)pr[1];
    }
    float e[18];
    const _Float16* ep = exb + u * 18;
    #pragma unroll
    for (int x = 0; x < 9; ++x) {
      f16x2 pr = *(const f16x2*)(ep + 2 * x);
      e[2 * x] = (float)pr[0]; e[2 * x + 1] = (float)pr[1];
    }
    #pragma unroll
    for (int v = 0; v < 18; ++v)
      #pragma unroll
      for (int j = 0; j < 13; ++j)
        acc[j] = fmaf(a[v + j], e[v], acc[j]);
  }
  if (active) {
    float* o = ws + XCB + ((size_t)(br * 4096 + bc0 + bcl)) * 169 + i * 13;
    #pragma unroll
    for (int j = 0; j < 13; ++j) o[j] = acc[j];
  }
}

// ---------------- fuse (1x1 conv + bn2 + relu) + final projection -------------
__global__ __launch_bounds__(256) void k_fuse(float* __restrict__ ws,
                                              const float* __restrict__ fus_b,
                                              const float* __restrict__ g2,
                                              const float* __restrict__ b2,
                                              const float* __restrict__ m2,
                                              const float* __restrict__ v2,
                                              const float* __restrict__ ow,
                                              const float* __restrict__ ob,
                                              float* __restrict__ out,
                                              int n_out, int br) {
  int ij = blockIdx.x, b = blockIdx.y;
  int t = threadIdx.x;
  __shared__ float xv[256];
  __shared__ float fv[256];
  xv[t] = ws[XCB + ((size_t)br * 4096 + b * 256 + t) * 169 + ij];
  __syncthreads();
  const float* fwt = ws + FWT + ((size_t)br << 16);
  float acc = 0.f;
  for (int c = 0; c < 256; ++c) acc = fmaf(fwt[(c << 8) + t], xv[c], acc);
  float s2 = g2[t] * rsqrtf(v2[t] + EPSBN);
  float f = (acc + fus_b[t] - m2[t]) * s2 + b2[t];
  fv[t] = fmaxf(f, 0.f);
  __syncthreads();
  int w = t >> 6, lane = t & 63;
  for (int po = w; po < n_out; po += 4) {
    float part = 0.f;
    #pragma unroll
    for (int q = 0; q < 4; ++q)
      part += ow[(po << 8) + lane + (q << 6)] * fv[lane + (q << 6)];
    for (int off = 32; off; off >>= 1) part += __shfl_down(part, off);
    if (lane == 0) out[((size_t)b * n_out + po) * 169 + ij] = part + ob[po];
  }
}

extern "C" void kernel_launch(void* const* d_in, const int* in_sizes, int n_in,
                              void* d_out, int out_size, void* d_ws, size_t ws_size,
                              hipStream_t stream) {
  const float* ex    = (const float*)d_in[0];
  const float* inst  = (const float*)d_in[1];
  const float* off_w = (const float*)d_in[2];
  const float* off_b = (const float*)d_in[3];
  const float* dcn_w = (const float*)d_in[4];
  const float* dcn_b = (const float*)d_in[5];
  const float* bn1_g = (const float*)d_in[6];
  const float* bn1_b = (const float*)d_in[7];
  const float* bn1_m = (const float*)d_in[8];
  const float* bn1_v = (const float*)d_in[9];
  const float* fus_w = (const float*)d_in[10];
  const float* fus_b = (const float*)d_in[11];
  const float* bn2_g = (const float*)d_in[12];
  const float* bn2_b = (const float*)d_in[13];
  const float* bn2_m = (const float*)d_in[14];
  const float* bn2_v = (const float*)d_in[15];
  const float* cls_w = (const float*)d_in[16];
  const float* cls_b = (const float*)d_in[17];
  const float* box_w = (const float*)d_in[18];
  const float* box_b = (const float*)d_in[19];
  float* out = (float*)d_out;
  float* ws  = (float*)d_ws;

  _Float16* xh_ex = (_Float16*)(ws + XF_EX);
  _Float16* xh_in = (_Float16*)(ws + XF_IN);
  _Float16* wpk   = (_Float16*)(ws + WPK);
  _Float16* owpk  = (_Float16*)(ws + OWPK);

  k_transpose<<<dim3(20, 16), 256, 0, stream>>>(ex,   xh_ex, 20, 20);
  k_transpose<<<dim3(32, 16), 256, 0, stream>>>(inst, xh_in, 32, 32);
  k_wpack <<<9216, 256, 0, stream>>>(dcn_w, wpk);
  k_owpack<<<1152, 256, 0, stream>>>(off_w, owpk);
  k_fwt   <<<512, 256, 0, stream>>>(fus_w, ws + FWT);
  k_offmfma<<<dim3(15, 16, 4), 256, 0, stream>>>(xh_ex, xh_in, owpk, off_b, ws);
  k_dgemm<<<dim3(15, 16, 4), 256, 0, stream>>>(xh_ex, xh_in, wpk, ws,
                                               dcn_b, bn1_g, bn1_b, bn1_m, bn1_v);
  k_xcorr3<<<dim3(256, 2), 256, 0, stream>>>(ws);
  k_fuse<<<dim3(169, 16), 256, 0, stream>>>(ws, fus_b, bn2_g, bn2_b, bn2_m, bn2_v,
                                            cls_w, cls_b, out, 4, 0);
  k_fuse<<<dim3(169, 16), 256, 0, stream>>>(ws, fus_b + 256, bn2_g + 256, bn2_b + 256,
                                            bn2_m + 256, bn2_v + 256, box_w, box_b,
                                            out + 10816, 16, 1);
}

// Round 8
// 330.148 us; speedup vs baseline: 8.6372x; 1.0240x over previous
//
#include <hip/hip_runtime.h>
#include <math.h>

#define EPSBN 1e-5f

typedef _Float16 f16x8 __attribute__((ext_vector_type(8)));
typedef _Float16 f16x2 __attribute__((ext_vector_type(2)));
typedef float    f32x4 __attribute__((ext_vector_type(4)));

__device__ __forceinline__ f16x8 splat8(float v) {
  _Float16 h = (_Float16)v;
  return (f16x8){h, h, h, h, h, h, h, h};
}

// decode compact tile index (42 tiles: 6 + 15 + 6 + 15)
__device__ __forceinline__ void tile_decode(int idx, int& h, int& tl) {
  if (idx < 6)       { h = 0; tl = idx; }
  else if (idx < 21) { h = 1; tl = idx - 6; }
  else if (idx < 27) { h = 2; tl = idx - 21; }
  else               { h = 3; tl = idx - 27; }
}

// ---------------- workspace layout (float-unit offsets) — validated ----------
static constexpr size_t XF_EX = 0;         // (16,20,20,256) f16
static constexpr size_t XF_IN = 819200;    // (16,32,32,256) f16
static constexpr size_t WPK   = 2916352;   // dcn_w f16 frag pack
static constexpr size_t OWPK  = 4096000;   // off_w f16 frag pack
static constexpr size_t FWT   = 4243456;   // (2,256,256) f32
static constexpr size_t OM0   = 4374528;   // (16,27,324) f32
static constexpr size_t OM1   = 4514496;   // (16,27,900)
static constexpr size_t OM2   = 4903296;
static constexpr size_t OM3   = 5043264;
static constexpr size_t HOUT0 = 5432064;   // (16,256,324) f32
static constexpr size_t HOUT1 = 6759168;   // (16,256,900) f32
static constexpr size_t HOUT2 = 10445568;
static constexpr size_t HOUT3 = 11772672;
static constexpr size_t XCB   = 15459072;  // (2,16,256,169) f32
// end 18227968 floats = 72.9 MB

// ---------------- NCHW fp32 -> NHWC f16 ----------------
__global__ __launch_bounds__(256) void k_transpose(const float* __restrict__ in,
                                                   _Float16* __restrict__ out,
                                                   int H, int W) {
  int y = blockIdx.x, b = blockIdx.y;
  __shared__ float tile[32][257];
  int t = threadIdx.x;
  int x = t & 31, cb = t >> 5;
  for (int c0 = 0; c0 < 256; c0 += 8) {
    int c = c0 + cb;
    if (x < W) tile[x][c] = in[(((size_t)b * 256 + c) * H + y) * W + x];
  }
  __syncthreads();
  for (int x2 = 0; x2 < W; ++x2)
    out[((((size_t)b * H + y) * W + x2) << 8) + t] = (_Float16)tile[x2][t];
}

// ---------------- dcn_w -> f16 MFMA-A fragment pack (validated) --------------
__global__ __launch_bounds__(256) void k_wpack(const float* __restrict__ w,
                                               _Float16* __restrict__ wp) {
  int idx = blockIdx.x * 256 + threadIdx.x;
  if (idx >= 4 * 9 * 8 * 16 * 64 * 8) return;
  int e  = idx & 7;
  int l  = (idx >> 3) & 63;
  int ot = (idx >> 9) & 15;
  int cs = (idx >> 13) & 7;
  int ht = idx >> 16;             // h*9 + tap
  int tap = ht % 9, h = ht / 9;
  int o = ot * 16 + (l & 15);
  int c = cs * 32 + 8 * (l >> 4) + e;
  wp[idx] = (_Float16)w[((size_t)((h * 256 + o) * 256 + c)) * 9 + tap];
}

// ---------------- off_w -> f16 MFMA-A fragment pack (M=27 padded to 32) ------
__global__ __launch_bounds__(256) void k_owpack(const float* __restrict__ w,
                                                _Float16* __restrict__ wp) {
  int idx = blockIdx.x * 256 + threadIdx.x;
  if (idx >= 4 * 9 * 8 * 2 * 64 * 8) return;
  int e  = idx & 7;
  int l  = (idx >> 3) & 63;
  int ot = (idx >> 9) & 1;
  int cs = (idx >> 10) & 7;
  int ht = idx >> 13;
  int tap = ht % 9, h = ht / 9;
  int o = ot * 16 + (l & 15);
  int c = cs * 32 + 8 * (l >> 4) + e;
  wp[idx] = (o < 27) ? (_Float16)w[((size_t)((h * 27 + o) * 256 + c)) * 9 + tap]
                     : (_Float16)0.f;
}

// ---------------- fus_w (2,256,256)[i][o][c] -> fwt [i][c][o] (fp32) ---------
__global__ __launch_bounds__(256) void k_fwt(const float* __restrict__ w,
                                             float* __restrict__ wt) {
  int idx = blockIdx.x * 256 + threadIdx.x;
  int o = idx & 255, c = (idx >> 8) & 255, i = idx >> 16;
  wt[idx] = w[(i << 16) + (o << 8) + c];
}

// ---------------- offset conv via MFMA, 512 thr, compact grid ----------------
__global__ __launch_bounds__(512) void k_offmfma(const _Float16* __restrict__ xh_ex,
                                                 const _Float16* __restrict__ xh_in,
                                                 const _Float16* __restrict__ owpk,
                                                 const float* __restrict__ off_b,
                                                 float* __restrict__ ws) {
  int h, tl;
  tile_decode(blockIdx.x, h, tl);
  const int b = blockIdx.y;
  const int HH[4] = {20, 32, 20, 32};
  const size_t OMO[4] = {OM0, OM1, OM2, OM3};
  const int H = HH[h], W = H, ho = H - 2, wo = W - 2, P = ho * wo;
  const int p0 = tl << 6;
  const _Float16* xh = ((h & 1) ? xh_in : xh_ex) + (((size_t)b * H * W) << 8);

  __shared__ __align__(16) _Float16 S[64 * 256];
  __shared__ int rowoff[64];

  const int t = threadIdx.x, lane = t & 63, wave = t >> 6;
  if (t < 64) {
    int p = min(p0 + t, P - 1);
    int i = p / wo, j = p - i * wo;
    rowoff[t] = (i * W + j) << 8;
  }
  const int ot = wave & 1, nn = wave >> 1;
  f32x4 acc = {0.f, 0.f, 0.f, 0.f};
  __syncthreads();

  const int o8 = t & 31;
  const int plb = t >> 5;                     // 0..15
  for (int tap = 0; tap < 9; ++tap) {
    const int ky = tap / 3, kx = tap - ky * 3;
    const int koff = (ky * W + kx) << 8;
    #pragma unroll
    for (int it = 0; it < 4; ++it) {
      int pl = it * 16 + plb;
      f16x8 v = *(const f16x8*)(xh + rowoff[pl] + koff + o8 * 8);
      *(f16x8*)((char*)S + pl * 512 + ((o8 * 16) ^ ((pl & 7) << 4))) = v;
    }
    __syncthreads();
    #pragma unroll
    for (int cs = 0; cs < 8; ++cs) {
      int ksg = tap * 8 + cs;
      const _Float16* ab = owpk + ((size_t)((h * 72 + ksg) * 2 + ot)) * 512 + lane * 8;
      f16x8 a = *(const f16x8*)(ab);
      int prow = nn * 16 + (lane & 15);
      f16x8 bf = *(const f16x8*)((char*)S + prow * 512 +
                                 ((cs * 64 + ((lane >> 4) << 4)) ^ ((prow & 7) << 4)));
      acc = __builtin_amdgcn_mfma_f32_16x16x32_f16(a, bf, acc, 0, 0, 0);
    }
    __syncthreads();
  }
  float* om = ws + OMO[h] + (size_t)b * 27 * P;
  int p = p0 + nn * 16 + (lane & 15);
  if (p < P) {
    #pragma unroll
    for (int r = 0; r < 4; ++r) {
      int o = ot * 16 + 4 * (lane >> 4) + r;
      if (o < 27) om[o * P + p] = acc[r] + off_b[h * 27 + o];
    }
  }
}

// ---------------- main deformable GEMM, 512 thr, compact grid ----------------
__global__ __launch_bounds__(512) void k_dgemm(const _Float16* __restrict__ xh_ex,
                                               const _Float16* __restrict__ xh_in,
                                               const _Float16* __restrict__ wpk,
                                               float* __restrict__ ws,
                                               const float* __restrict__ dcn_b,
                                               const float* __restrict__ g1,
                                               const float* __restrict__ b1,
                                               const float* __restrict__ m1,
                                               const float* __restrict__ v1) {
  int h, tl;
  tile_decode(blockIdx.x, h, tl);
  const int HH4[4] = {20, 32, 20, 32};
  const size_t OMO[4] = {OM0, OM1, OM2, OM3};
  const size_t HOO[4] = {HOUT0, HOUT1, HOUT2, HOUT3};
  const int H = HH4[h], W = H, ho = H - 2, wo = W - 2, P = ho * wo;
  const int b = blockIdx.y;
  const int p0 = tl << 6;
  const _Float16* xh = (h & 1) ? xh_in : xh_ex;
  const float* om = ws + OMO[h] + (size_t)b * 27 * P;
  float* outp = ws + HOO[h] + (size_t)b * 256 * P;

  __shared__ float4 swt4[576];
  __shared__ int4   sad4[576];
  __shared__ __align__(16) _Float16 S[64 * 256];

  const int t = threadIdx.x, lane = t & 63, wave = t >> 6;

  // Phase A: per-(pixel,tap) bilinear weights (mask+validity folded) & addrs
  for (int e = t; e < 576; e += 512) {
    int pl = e / 9, k = e - pl * 9;
    float w4[4] = {0.f, 0.f, 0.f, 0.f};
    int a4[4] = {0, 0, 0, 0};
    int p = p0 + pl;
    if (p < P) {
      int i = p / wo, j = p - i * wo;
      float oy = om[(2 * k) * P + p];
      float ox = om[(2 * k + 1) * P + p];
      float mm = om[(18 + k) * P + p];
      float msk = 1.f / (1.f + __expf(-mm));
      int ky = k / 3, kx = k - ky * 3;
      float py = (float)(ky + i) + oy;
      float px = (float)(kx + j) + ox;
      float fy = floorf(py), fx = floorf(px);
      int y0 = (int)fy, x0 = (int)fx;
      float dy = py - fy, dx = px - fx;
      #pragma unroll
      for (int q = 0; q < 4; ++q) {
        int yy = y0 + (q >> 1), xx = x0 + (q & 1);
        bool vld = (yy >= 0) && (yy < H) && (xx >= 0) && (xx < W);
        int yc = min(max(yy, 0), H - 1), xc = min(max(xx, 0), W - 1);
        float wq = ((q >> 1) ? dy : 1.f - dy) * ((q & 1) ? dx : 1.f - dx);
        w4[q] = vld ? wq * msk : 0.f;
        a4[q] = ((b * H + yc) * W + xc) << 8;
      }
    }
    swt4[e] = make_float4(w4[0], w4[1], w4[2], w4[3]);
    sad4[e] = make_int4(a4[0], a4[1], a4[2], a4[3]);
  }

  f32x4 acc[2][4];
  #pragma unroll
  for (int a = 0; a < 2; ++a)
    #pragma unroll
    for (int n = 0; n < 4; ++n) acc[a][n] = (f32x4){0.f, 0.f, 0.f, 0.f};

  __syncthreads();

  const int o8 = t & 31;
  const int plb = t >> 5;                 // 0..15
  for (int tap = 0; tap < 9; ++tap) {
    // Phase B: sample 64p x 256c f16 into swizzled LDS
    #pragma unroll
    for (int it = 0; it < 4; ++it) {
      int pl = it * 16 + plb;
      float4 w4 = swt4[pl * 9 + tap];
      int4   a4 = sad4[pl * 9 + tap];
      const _Float16* xb = xh + o8 * 8;
      f16x8 x0 = *(const f16x8*)(xb + a4.x);
      f16x8 x1 = *(const f16x8*)(xb + a4.y);
      f16x8 x2 = *(const f16x8*)(xb + a4.z);
      f16x8 x3 = *(const f16x8*)(xb + a4.w);
      f16x8 s = x0 * splat8(w4.x) + x1 * splat8(w4.y) + x2 * splat8(w4.z) + x3 * splat8(w4.w);
      *(f16x8*)((char*)S + pl * 512 + ((o8 * 16) ^ ((pl & 7) << 4))) = s;
    }
    __syncthreads();
    // Phase C: 8 K-steps x (2 otile x 4 ptile) MFMA per wave
    #pragma unroll
    for (int cs = 0; cs < 8; ++cs) {
      int ksg = tap * 8 + cs;
      const _Float16* ab = wpk + ((size_t)(h * 72 + ksg) * 16 + wave * 2) * 512 + lane * 8;
      f16x8 A0 = *(const f16x8*)(ab);
      f16x8 A1 = *(const f16x8*)(ab + 512);
      f16x8 B[4];
      #pragma unroll
      for (int n = 0; n < 4; ++n) {
        int prow = n * 16 + (lane & 15);
        B[n] = *(const f16x8*)((char*)S + prow * 512 +
                               ((cs * 64 + ((lane >> 4) << 4)) ^ ((prow & 7) << 4)));
      }
      #pragma unroll
      for (int n = 0; n < 4; ++n) {
        acc[0][n] = __builtin_amdgcn_mfma_f32_16x16x32_f16(A0, B[n], acc[0][n], 0, 0, 0);
        acc[1][n] = __builtin_amdgcn_mfma_f32_16x16x32_f16(A1, B[n], acc[1][n], 0, 0, 0);
      }
    }
    __syncthreads();
  }

  // epilogue: + dcn_b then bn1; out layout (B,256o,P) fp32 (validated)
  #pragma unroll
  for (int a = 0; a < 2; ++a) {
    int obase = (wave * 2 + a) * 16 + 4 * (lane >> 4);
    #pragma unroll
    for (int r = 0; r < 4; ++r) {
      int o = obase + r;
      float al = g1[h * 256 + o] * rsqrtf(v1[h * 256 + o] + EPSBN);
      float be = (dcn_b[h * 256 + o] - m1[h * 256 + o]) * al + b1[h * 256 + o];
      #pragma unroll
      for (int n = 0; n < 4; ++n) {
        int p = p0 + n * 16 + (lane & 15);
        if (p < P) outp[(size_t)o * P + p] = fmaf(acc[a][n][r], al, be);
      }
    }
  }
}

// ---------------- xcorr v3 (validated round-7) -------------------------------
__global__ __launch_bounds__(256) void k_xcorr3(float* __restrict__ ws) {
  const int br = blockIdx.y;
  const int bc0 = blockIdx.x << 4;
  const float* exg = ws + (br ? HOUT2 : HOUT0) + (size_t)bc0 * 324;
  const float* ing = ws + (br ? HOUT3 : HOUT1) + (size_t)bc0 * 900;
  __shared__ __align__(16) _Float16 exl[16 * 324];
  __shared__ __align__(16) _Float16 inl[16 * 960];   // rows padded 30 -> 32
  const int t = threadIdx.x;
  for (int idx = t; idx < 16 * 324; idx += 256)
    exl[idx] = (_Float16)exg[idx];
  for (int idx = t; idx < 16 * 960; idx += 256) {
    int c = idx & 31;
    int rr = idx >> 5;                                // bcl*30 + row
    inl[idx] = (c < 30) ? (_Float16)ing[rr * 30 + c] : (_Float16)0.f;
  }
  __syncthreads();
  const int lane = t & 63, wave = t >> 6;
  const int sub = lane / 13;
  const int i = lane - sub * 13;
  const bool active = sub < 4;
  const int bcl = wave * 4 + (active ? sub : 0);
  float acc[13];
  #pragma unroll
  for (int j = 0; j < 13; ++j) acc[j] = 0.f;
  const _Float16* inb = inl + bcl * 960;
  const _Float16* exb = exl + bcl * 324;
  for (int u = 0; u < 18; ++u) {
    float a[30];
    const _Float16* rp = inb + (i + u) * 32;
    #pragma unroll
    for (int x = 0; x < 15; ++x) {
      f16x2 pr = *(const f16x2*)(rp + 2 * x);
      a[2 * x] = (float)pr[0]; a[2 * x + 1] = (float)pr[1];
    }
    float e[18];
    const _Float16* ep = exb + u * 18;
    #pragma unroll
    for (int x = 0; x < 9; ++x) {
      f16x2 pr = *(const f16x2*)(ep + 2 * x);
      e[2 * x] = (float)pr[0]; e[2 * x + 1] = (float)pr[1];
    }
    #pragma unroll
    for (int v = 0; v < 18; ++v)
      #pragma unroll
      for (int j = 0; j < 13; ++j)
        acc[j] = fmaf(a[v + j], e[v], acc[j]);
  }
  if (active) {
    float* o = ws + XCB + ((size_t)(br * 4096 + bc0 + bcl)) * 169 + i * 13;
    #pragma unroll
    for (int j = 0; j < 13; ++j) o[j] = acc[j];
  }
}

// ---------------- fuse v2: 13 pixels/block, both branches, one launch --------
__global__ __launch_bounds__(256) void k_fuse2(float* __restrict__ ws,
                                               const float* __restrict__ fus_b,
                                               const float* __restrict__ g2,
                                               const float* __restrict__ b2,
                                               const float* __restrict__ m2,
                                               const float* __restrict__ v2,
                                               const float* __restrict__ cls_w,
                                               const float* __restrict__ cls_b,
                                               const float* __restrict__ box_w,
                                               const float* __restrict__ box_b,
                                               float* __restrict__ out) {
  const int ij0 = blockIdx.x * 13;
  const int b = blockIdx.y;
  const int br = blockIdx.z;
  const int n_out = br ? 16 : 4;
  const float* ow = br ? box_w : cls_w;
  const float* ob = br ? box_b : cls_b;
  float* outp = out + (br ? (size_t)10816 : 0);

  __shared__ float xv[256 * 13];
  __shared__ float fv[13 * 257];
  const int t = threadIdx.x;
  const float* src = ws + XCB + ((size_t)br * 4096 + b * 256) * 169;
  for (int idx = t; idx < 256 * 13; idx += 256) {
    int c = idx / 13, j = idx - c * 13;
    xv[idx] = src[(size_t)c * 169 + ij0 + j];
  }
  __syncthreads();

  // 1x1 conv over c: thread t = output channel o
  const float* fwt = ws + FWT + ((size_t)br << 16) + t;
  float acc[13];
  #pragma unroll
  for (int j = 0; j < 13; ++j) acc[j] = 0.f;
  for (int c = 0; c < 256; ++c) {
    float wv = fwt[c << 8];
    #pragma unroll
    for (int j = 0; j < 13; ++j)
      acc[j] = fmaf(wv, xv[c * 13 + j], acc[j]);
  }
  float s2 = g2[br * 256 + t] * rsqrtf(v2[br * 256 + t] + EPSBN);
  float fb = fus_b[br * 256 + t], mm = m2[br * 256 + t], bb = b2[br * 256 + t];
  #pragma unroll
  for (int j = 0; j < 13; ++j)
    fv[j * 257 + t] = fmaxf((acc[j] + fb - mm) * s2 + bb, 0.f);
  __syncthreads();

  // final projection: 16-lane groups reduce 256 channels
  const int g = t >> 4, l16 = t & 15;
  for (int wi = g; wi < 13 * n_out; wi += 16) {
    int j = wi / n_out, po = wi - j * n_out;
    float part = 0.f;
    #pragma unroll
    for (int q = 0; q < 16; ++q)
      part = fmaf(ow[(po << 8) + l16 + (q << 4)], fv[j * 257 + l16 + (q << 4)], part);
    #pragma unroll
    for (int off = 8; off; off >>= 1) part += __shfl_xor(part, off);
    if (l16 == 0)
      outp[((size_t)b * n_out + po) * 169 + ij0 + j] = part + ob[po];
  }
}

extern "C" void kernel_launch(void* const* d_in, const int* in_sizes, int n_in,
                              void* d_out, int out_size, void* d_ws, size_t ws_size,
                              hipStream_t stream) {
  const float* ex    = (const float*)d_in[0];
  const float* inst  = (const float*)d_in[1];
  const float* off_w = (const float*)d_in[2];
  const float* off_b = (const float*)d_in[3];
  const float* dcn_w = (const float*)d_in[4];
  const float* dcn_b = (const float*)d_in[5];
  const float* bn1_g = (const float*)d_in[6];
  const float* bn1_b = (const float*)d_in[7];
  const float* bn1_m = (const float*)d_in[8];
  const float* bn1_v = (const float*)d_in[9];
  const float* fus_w = (const float*)d_in[10];
  const float* fus_b = (const float*)d_in[11];
  const float* bn2_g = (const float*)d_in[12];
  const float* bn2_b = (const float*)d_in[13];
  const float* bn2_m = (const float*)d_in[14];
  const float* bn2_v = (const float*)d_in[15];
  const float* cls_w = (const float*)d_in[16];
  const float* cls_b = (const float*)d_in[17];
  const float* box_w = (const float*)d_in[18];
  const float* box_b = (const float*)d_in[19];
  float* out = (float*)d_out;
  float* ws  = (float*)d_ws;

  _Float16* xh_ex = (_Float16*)(ws + XF_EX);
  _Float16* xh_in = (_Float16*)(ws + XF_IN);
  _Float16* wpk   = (_Float16*)(ws + WPK);
  _Float16* owpk  = (_Float16*)(ws + OWPK);

  k_transpose<<<dim3(20, 16), 256, 0, stream>>>(ex,   xh_ex, 20, 20);
  k_transpose<<<dim3(32, 16), 256, 0, stream>>>(inst, xh_in, 32, 32);
  k_wpack <<<9216, 256, 0, stream>>>(dcn_w, wpk);
  k_owpack<<<1152, 256, 0, stream>>>(off_w, owpk);
  k_fwt   <<<512, 256, 0, stream>>>(fus_w, ws + FWT);
  k_offmfma<<<dim3(42, 16), 512, 0, stream>>>(xh_ex, xh_in, owpk, off_b, ws);
  k_dgemm<<<dim3(42, 16), 512, 0, stream>>>(xh_ex, xh_in, wpk, ws,
                                            dcn_b, bn1_g, bn1_b, bn1_m, bn1_v);
  k_xcorr3<<<dim3(256, 2), 256, 0, stream>>>(ws);
  k_fuse2<<<dim3(13, 16, 2), 256, 0, stream>>>(ws, fus_b, bn2_g, bn2_b, bn2_m, bn2_v,
                                               cls_w, cls_b, box_w, box_b, out);
}